// Round 5
// baseline (456.661 us; speedup 1.0000x reference)
//
#include <hip/hip_runtime.h>
#include <hip/hip_bf16.h>

typedef unsigned short u16;
typedef unsigned int u32;
typedef __attribute__((ext_vector_type(8))) __bf16 bf16x8;
typedef __attribute__((ext_vector_type(4))) float f32x4;

#define GLD16(g, l) __builtin_amdgcn_global_load_lds((const __attribute__((address_space(1))) u32*)(g), (__attribute__((address_space(3))) u32*)(l), 16, 0, 0)

__device__ __forceinline__ u16 f2bf(float f) {
    u32 u = __float_as_uint(f);
    u += 0x7FFFu + ((u >> 16) & 1u);
    return (u16)(u >> 16);
}

__device__ __forceinline__ u32 flipf(float f) {
    u32 u = __float_as_uint(f);
    return (u >> 31) ? ~u : (u | 0x80000000u);
}

__device__ __forceinline__ float unflipf(u32 k) {
    return __uint_as_float((k >> 31) ? (k ^ 0x80000000u) : ~k);
}

// bilinear 14->28 taps (jax.image.resize, half-pixel, edge-renormalized)
__device__ __forceinline__ void taps(int o, int& i0, int& i1, float& w0, float& w1) {
    int k = (o - 1) >> 1;
    float fy = (0.5f * (float)o - 0.25f) - (float)k;
    i0 = k; i1 = k + 1;
    w0 = 1.0f - fy; w1 = fy;
    if (i0 < 0)  { i0 = 0;  w0 = 0.0f; w1 = 1.0f; }
    if (i1 > 13) { i1 = 13; w1 = 0.0f; w0 = 1.0f; }
}

// merged: [blocks 0..16383] memory-bank fp32->bf16 + norms (+minkey init)
//         [blocks 16384..19519] U = 3x3 box-sum of paired feat3 channels
__global__ __launch_bounds__(256) void prep_kernel(
    const float* __restrict__ f3, float* __restrict__ U,
    const float* __restrict__ mb, u16* __restrict__ mbb, float* __restrict__ mb2,
    u32* __restrict__ minkey) {
    int bid = blockIdx.x, tid = threadIdx.x;
    if (bid < 16384) {
        float4 v = ((const float4*)(mb + (size_t)bid * 1024))[tid];
        ushort4 o;
        o.x = f2bf(v.x); o.y = f2bf(v.y); o.z = f2bf(v.z); o.w = f2bf(v.w);
        ((ushort4*)(mbb + (size_t)bid * 1024))[tid] = o;
        float ssq = v.x * v.x + v.y * v.y + v.z * v.z + v.w * v.w;
        for (int s = 32; s; s >>= 1) ssq += __shfl_down(ssq, s);
        __shared__ float sm[4];
        if ((tid & 63) == 0) sm[tid >> 6] = ssq;
        __syncthreads();
        if (tid == 0) mb2[bid] = sm[0] + sm[1] + sm[2] + sm[3];
        if (bid < 25) {
            int i = bid * 256 + tid;
            if (i < 6400) minkey[i] = 0xFFFFFFFFu;
        }
    } else {
        int idx = (bid - 16384) * 256 + tid;
        if (idx >= 8 * 512 * 196) return;
        int b = idx / (512 * 196);
        int rem = idx % (512 * 196);
        int t = rem / 196;
        int yx = rem % 196;
        int y = yx / 14, x = yx % 14;
        const float* p0 = f3 + ((size_t)(b * 1024 + 2 * t)) * 196;
        const float* p1 = p0 + 196;
        float s = 0.f;
        #pragma unroll
        for (int dy = -1; dy <= 1; ++dy) {
            int yy = y + dy; if ((unsigned)yy >= 14u) continue;
            #pragma unroll
            for (int dx = -1; dx <= 1; ++dx) {
                int xx = x + dx; if ((unsigned)xx >= 14u) continue;
                s += p0[yy * 14 + xx] + p1[yy * 14 + xx];
            }
        }
        U[idx] = s;
    }
}

// q[n, 0:512] = weighted 3x3 mean of feat2; q[n, 512+t] = bilinear(U)[h,w]/18
__global__ __launch_bounds__(256) void q_kernel(const float* __restrict__ feat2, const float* __restrict__ U,
                                                u16* __restrict__ qb, float* __restrict__ qn2) {
    int n = blockIdx.x;
    int b = n / 784;
    int hw = n % 784;
    int h = hw / 28, w = hw % 28;
    int tid = threadIdx.x;
    int y0, y1, x0, x1; float wy0, wy1, wx0, wx1;
    taps(h, y0, y1, wy0, wy1);
    taps(w, x0, x1, wx0, wx1);
    float ssq = 0.f;
    #pragma unroll
    for (int k = 0; k < 4; ++k) {
        int d = tid + k * 256;
        float val;
        if (d < 512) {
            const float* p = feat2 + ((size_t)(b * 512 + d)) * 784;
            float s = 0.f;
            #pragma unroll
            for (int di = -1; di <= 1; ++di) {
                int y = h + di; if ((unsigned)y >= 28u) continue;
                #pragma unroll
                for (int dj = -1; dj <= 1; ++dj) {
                    int x = w + dj; if ((unsigned)x >= 28u) continue;
                    float v = p[y * 28 + x];
                    s += (di == 0 && dj == 0) ? 2.f * v : v;
                }
            }
            val = s * 0.1f;
        } else {
            const float* up = U + ((size_t)(b * 512 + (d - 512))) * 196;
            float v00 = up[y0 * 14 + x0], v01 = up[y0 * 14 + x1];
            float v10 = up[y1 * 14 + x0], v11 = up[y1 * 14 + x1];
            val = (wy0 * (wx0 * v00 + wx1 * v01) + wy1 * (wx0 * v10 + wx1 * v11)) * (1.f / 18.f);
        }
        ssq += val * val;
        qb[(size_t)n * 1024 + d] = f2bf(val);
    }
    for (int s = 32; s; s >>= 1) ssq += __shfl_down(ssq, s);
    __shared__ float sm[4];
    if ((tid & 63) == 0) sm[tid >> 6] = ssq;
    __syncthreads();
    if (tid == 0) qn2[n] = sm[0] + sm[1] + sm[2] + sm[3];
}

// 256x256-tile BK=64 bf16 MFMA GEMM. Pipelined fragment reads (counted lgkmcnt)
// + DEEP DMA pipeline: A double-buffered, B TRIPLE-buffered (staged 2 tiles
// ahead), steady vmcnt(6) once per tile. LDS = 160KB exactly. Fully unrolled.
// M=6400 (q rows, 6272 real), N=16384, K=1024 -> 16 K-tiles.
__global__ __launch_bounds__(512, 1) void gemm_min_kernel(
    const u16* __restrict__ qb, const u16* __restrict__ mbb,
    const float* __restrict__ qn2, const float* __restrict__ mb2,
    u32* __restrict__ minkeys) {
    __shared__ __align__(16) u16 smem[81920];   // A: 2x16384, B: 3x16384 (u16)

    const int tid = threadIdx.x;
    const int wid = tid >> 6;
    const int lane = tid & 63;
    const int wm = wid >> 2;   // 2 M-waves
    const int wn = wid & 3;    // 4 N-waves

    // XCD-aware bijective swizzle: 1600 blocks, 8 XCDs, 200/XCD.
    const int flat = blockIdx.x;
    const int swz = (flat & 7) * 200 + (flat >> 3);
    const int q0 = (swz % 25) * 256;   // q-row (M) panel
    const int m0 = (swz / 25) * 256;   // memory-bank (N) panel

    // staging: half-tile = 128 rows x 64 cols = 16 KB; 2 gload_lds/thread.
    // LDS dest linear; global source slot XOR-swizzled with row&7 (= lane>>3).
    const int rA = wid * 16 + (lane >> 3);            // + j*8
    const int srcslot = (lane & 7) ^ (lane >> 3);
    size_t baseA[2], baseB[2];
    u32 ldst[2];
    #pragma unroll
    for (int j = 0; j < 2; ++j) {
        baseA[j] = (size_t)(q0 + rA + j * 8) * 1024 + srcslot * 8;
        baseB[j] = (size_t)(m0 + rA + j * 8) * 1024 + srcslot * 8;
        ldst[j] = (wid * 2 + j) * 512;                // u16 idx, wave-uniform
    }

    #define STAGE_A(T, H) { const int _t = (T), _h = (H); \
        GLD16(qb + baseA[0] + (size_t)_h * 131072 + _t * 64, &smem[(_t & 1) * 16384 + _h * 8192 + ldst[0]]); \
        GLD16(qb + baseA[1] + (size_t)_h * 131072 + _t * 64, &smem[(_t & 1) * 16384 + _h * 8192 + ldst[1]]); }
    #define STAGE_B(T, H) { const int _t = (T), _h = (H); \
        GLD16(mbb + baseB[0] + (size_t)_h * 131072 + _t * 64, &smem[32768 + (_t % 3) * 16384 + _h * 8192 + ldst[0]]); \
        GLD16(mbb + baseB[1] + (size_t)_h * 131072 + _t * 64, &smem[32768 + (_t % 3) * 16384 + _h * 8192 + ldst[1]]); }

    // fragment read addressing (row&7 == lane&7 for all frags)
    const u32 arow = (u32)(wm * 128 + (lane & 15)) * 64;   // + m*1024
    const u32 brow = (u32)(wn * 64 + (lane & 15)) * 64;    // + n*1024
    const u32 sl0 = (u32)(((lane >> 4)) ^ (lane & 7)) * 8;       // kk=0
    const u32 sl1 = (u32)((4 + (lane >> 4)) ^ (lane & 7)) * 8;   // kk=1

    f32x4 acc[8][4] = {};
    bf16x8 aP[4][2], aQ[4][2], b01[2][2], b23[2][2];

    #define MFMA8(M0, AARR, BARR, N0) \
        _Pragma("unroll") for (int m = 0; m < 4; ++m) \
            _Pragma("unroll") for (int n = 0; n < 2; ++n) { \
                acc[(M0) + m][(N0) + n] = __builtin_amdgcn_mfma_f32_16x16x32_bf16(AARR[m][0], BARR[n][0], acc[(M0) + m][(N0) + n], 0, 0, 0); \
                acc[(M0) + m][(N0) + n] = __builtin_amdgcn_mfma_f32_16x16x32_bf16(AARR[m][1], BARR[n][1], acc[(M0) + m][(N0) + n], 0, 0, 0); }

    #define VMW(N) { asm volatile("s_waitcnt vmcnt(" #N ")" ::: "memory"); \
                     __builtin_amdgcn_s_barrier(); \
                     __builtin_amdgcn_sched_barrier(0); }

    // One K-tile. AC holds alo of tile T (read at prev p4); b01 likewise.
    // Staging: p1/p2 -> B(T+2) halves; p3/p4 -> A(T+2) halves (A(T) consumed
    // by the p2-end barrier). End-of-tile vmcnt(6) => A(T+1),B(T+1) landed.
    #define TILE_BODY(T, AC, AN, STB, STA, PREF, VMWAIT) { \
        const u16* Ab  = smem + ((T) & 1) * 16384; \
        const u16* Bb  = smem + 32768 + ((T) % 3) * 16384; \
        const u16* Abn = smem + (((T) + 1) & 1) * 16384; \
        const u16* Bbn = smem + 32768 + (((T) + 1) % 3) * 16384; \
        /* p1: read ahi->AN; MFMA mlo x b01 */ \
        _Pragma("unroll") for (int m = 0; m < 4; ++m) { \
            AN[m][0] = *(const bf16x8*)&Ab[arow + (4 + m) * 1024 + sl0]; \
            AN[m][1] = *(const bf16x8*)&Ab[arow + (4 + m) * 1024 + sl1]; } \
        if (STB) STAGE_B((T) + 2, 0); \
        asm volatile("s_waitcnt lgkmcnt(8)" ::: "memory"); \
        __builtin_amdgcn_sched_barrier(0); \
        __builtin_amdgcn_s_setprio(1); \
        MFMA8(0, AC, b01, 0); \
        __builtin_amdgcn_s_setprio(0); \
        /* p2: read b23; MFMA mhi x b01 */ \
        _Pragma("unroll") for (int n = 0; n < 2; ++n) { \
            b23[n][0] = *(const bf16x8*)&Bb[brow + (2 + n) * 1024 + sl0]; \
            b23[n][1] = *(const bf16x8*)&Bb[brow + (2 + n) * 1024 + sl1]; } \
        if (STB) STAGE_B((T) + 2, 1); \
        asm volatile("s_waitcnt lgkmcnt(4)" ::: "memory"); \
        __builtin_amdgcn_sched_barrier(0); \
        __builtin_amdgcn_s_setprio(1); \
        MFMA8(4, AN, b01, 0); \
        __builtin_amdgcn_s_setprio(0); \
        __builtin_amdgcn_s_barrier(); /* all A(T)/B01(T) reads complete */ \
        /* p3: MFMA mhi x b23 */ \
        if (STA) STAGE_A((T) + 2, 0); \
        asm volatile("s_waitcnt lgkmcnt(0)" ::: "memory"); \
        __builtin_amdgcn_sched_barrier(0); \
        __builtin_amdgcn_s_setprio(1); \
        MFMA8(4, AN, b23, 2); \
        __builtin_amdgcn_s_setprio(0); \
        /* p4: counted vmcnt + barrier; prefetch next alo/b01; MFMA mlo x b23 */ \
        VMWAIT \
        if (PREF) { \
            _Pragma("unroll") for (int m = 0; m < 4; ++m) { \
                AN[m][0] = *(const bf16x8*)&Abn[arow + m * 1024 + sl0]; \
                AN[m][1] = *(const bf16x8*)&Abn[arow + m * 1024 + sl1]; } \
            _Pragma("unroll") for (int n = 0; n < 2; ++n) { \
                b01[n][0] = *(const bf16x8*)&Bbn[brow + n * 1024 + sl0]; \
                b01[n][1] = *(const bf16x8*)&Bbn[brow + n * 1024 + sl1]; } } \
        if (STA) STAGE_A((T) + 2, 1); \
        __builtin_amdgcn_s_setprio(1); \
        MFMA8(0, AC, b23, 2); \
        __builtin_amdgcn_s_setprio(0); \
    }

    // ---- prologue: A0,B0,A1,B1 in flight; wait A0+B0; pre-read tile-0 frags
    STAGE_A(0, 0); STAGE_A(0, 1);
    STAGE_B(0, 0); STAGE_B(0, 1);
    STAGE_A(1, 0); STAGE_A(1, 1);
    STAGE_B(1, 0); STAGE_B(1, 1);
    asm volatile("s_waitcnt vmcnt(8)" ::: "memory");
    __builtin_amdgcn_s_barrier();
    __builtin_amdgcn_sched_barrier(0);
    {
        const u16* Ab0 = smem;
        const u16* Bb0 = smem + 32768;
        #pragma unroll
        for (int m = 0; m < 4; ++m) {
            aP[m][0] = *(const bf16x8*)&Ab0[arow + m * 1024 + sl0];
            aP[m][1] = *(const bf16x8*)&Ab0[arow + m * 1024 + sl1];
        }
        #pragma unroll
        for (int n = 0; n < 2; ++n) {
            b01[n][0] = *(const bf16x8*)&Bb0[brow + n * 1024 + sl0];
            b01[n][1] = *(const bf16x8*)&Bb0[brow + n * 1024 + sl1];
        }
    }

    TILE_BODY(0,  aP, aQ, 1, 1, 1, VMW(6))
    TILE_BODY(1,  aQ, aP, 1, 1, 1, VMW(6))
    TILE_BODY(2,  aP, aQ, 1, 1, 1, VMW(6))
    TILE_BODY(3,  aQ, aP, 1, 1, 1, VMW(6))
    TILE_BODY(4,  aP, aQ, 1, 1, 1, VMW(6))
    TILE_BODY(5,  aQ, aP, 1, 1, 1, VMW(6))
    TILE_BODY(6,  aP, aQ, 1, 1, 1, VMW(6))
    TILE_BODY(7,  aQ, aP, 1, 1, 1, VMW(6))
    TILE_BODY(8,  aP, aQ, 1, 1, 1, VMW(6))
    TILE_BODY(9,  aQ, aP, 1, 1, 1, VMW(6))
    TILE_BODY(10, aP, aQ, 1, 1, 1, VMW(6))
    TILE_BODY(11, aQ, aP, 1, 1, 1, VMW(6))
    TILE_BODY(12, aP, aQ, 1, 1, 1, VMW(6))
    TILE_BODY(13, aQ, aP, 1, 1, 1, VMW(6))
    TILE_BODY(14, aP, aQ, 0, 0, 1, VMW(0))
    TILE_BODY(15, aQ, aP, 0, 0, 0, )

    // ---- epilogue: fused min over memory dim (rowmin aliases A-buffer)
    __syncthreads();
    u32* rowmin = (u32*)smem;
    if (tid < 256) rowmin[tid] = 0xFFFFFFFFu;
    __syncthreads();

    float mb2v[4];
    #pragma unroll
    for (int n = 0; n < 4; ++n) mb2v[n] = mb2[m0 + wn * 64 + n * 16 + (lane & 15)];

    #pragma unroll
    for (int m = 0; m < 8; ++m) {
        #pragma unroll
        for (int r = 0; r < 4; ++r) {
            const int qrow = wm * 128 + m * 16 + (lane >> 4) * 4 + r;
            const float qq = qn2[q0 + qrow];
            float v = 3.4e38f;
            #pragma unroll
            for (int n = 0; n < 4; ++n) {
                float d2 = qq + mb2v[n] - 2.0f * acc[m][n][r];
                v = fminf(v, d2);
            }
            #pragma unroll
            for (int s = 1; s < 16; s <<= 1) v = fminf(v, __shfl_xor(v, s));
            if ((lane & 15) == 0) atomicMin(&rowmin[qrow], flipf(v));
        }
    }
    __syncthreads();
    if (tid < 256) atomicMin(minkeys + q0 + tid, rowmin[tid]);
}

// per-image max + write patch scores
__global__ __launch_bounds__(256) void final_kernel(const u32* __restrict__ keys, float* __restrict__ out) {
    int b = blockIdx.x, tid = threadIdx.x;
    float mx = -3.4e38f;
    for (int i = tid; i < 784; i += 256) {
        float f = unflipf(keys[b * 784 + i]);
        out[8 + b * 784 + i] = f;
        mx = fmaxf(mx, f);
    }
    for (int s = 32; s; s >>= 1) mx = fmaxf(mx, __shfl_down(mx, s));
    __shared__ float sm[4];
    if ((tid & 63) == 0) sm[tid >> 6] = mx;
    __syncthreads();
    if (tid == 0) out[b] = fmaxf(fmaxf(sm[0], sm[1]), fmaxf(sm[2], sm[3]));
}

extern "C" void kernel_launch(void* const* d_in, const int* in_sizes, int n_in,
                              void* d_out, int out_size, void* d_ws, size_t ws_size,
                              hipStream_t stream) {
    const float* feat2 = (const float*)d_in[0];   // [8,512,28,28]
    const float* feat3 = (const float*)d_in[1];   // [8,1024,14,14]
    const float* mb    = (const float*)d_in[2];   // [16384,1024]
    float* out = (float*)d_out;                   // [8] image + [8,28,28] patch

    char* ws = (char*)d_ws;
    float* U      = (float*)(ws);                  // 3,211,264 B
    u16*   qb     = (u16*)  (ws + 3211264);        // 6400*1024*2 = 13,107,200 B (pad rows unused)
    u16*   mbb    = (u16*)  (ws + 16318464);       // 33,554,432 B
    float* qn2    = (float*)(ws + 49872896);       // 25,088 B
    float* mb2    = (float*)(ws + 49897984);       // 65,536 B
    u32*   minkey = (u32*)  (ws + 49963520);       // 25,600 B

    prep_kernel<<<19520, 256, 0, stream>>>(feat3, U, mb, mbb, mb2, minkey);
    q_kernel<<<6272, 256, 0, stream>>>(feat2, U, qb, qn2);
    gemm_min_kernel<<<1600, 512, 0, stream>>>(qb, mbb, qn2, mb2, minkey);
    final_kernel<<<8, 256, 0, stream>>>(minkey, out);
}

// Round 6
// 391.014 us; speedup vs baseline: 1.1679x; 1.1679x over previous
//
#include <hip/hip_runtime.h>
#include <hip/hip_bf16.h>

typedef unsigned short u16;
typedef unsigned int u32;
typedef __attribute__((ext_vector_type(8))) __bf16 bf16x8;
typedef __attribute__((ext_vector_type(4))) float f32x4;

#define GLD16(g, l) __builtin_amdgcn_global_load_lds((const __attribute__((address_space(1))) u32*)(g), (__attribute__((address_space(3))) u32*)(l), 16, 0, 0)

__device__ __forceinline__ u16 f2bf(float f) {
    u32 u = __float_as_uint(f);
    u += 0x7FFFu + ((u >> 16) & 1u);
    return (u16)(u >> 16);
}

__device__ __forceinline__ u32 flipf(float f) {
    u32 u = __float_as_uint(f);
    return (u >> 31) ? ~u : (u | 0x80000000u);
}

__device__ __forceinline__ float unflipf(u32 k) {
    return __uint_as_float((k >> 31) ? (k ^ 0x80000000u) : ~k);
}

// bilinear 14->28 taps (jax.image.resize, half-pixel, edge-renormalized)
__device__ __forceinline__ void taps(int o, int& i0, int& i1, float& w0, float& w1) {
    int k = (o - 1) >> 1;
    float fy = (0.5f * (float)o - 0.25f) - (float)k;
    i0 = k; i1 = k + 1;
    w0 = 1.0f - fy; w1 = fy;
    if (i0 < 0)  { i0 = 0;  w0 = 0.0f; w1 = 1.0f; }
    if (i1 > 13) { i1 = 13; w1 = 0.0f; w0 = 1.0f; }
}

// merged: [blocks 0..16383] memory-bank fp32->bf16 + norms (+minkey init)
//         [blocks 16384..19519] U = 3x3 box-sum of paired feat3 channels
__global__ __launch_bounds__(256) void prep_kernel(
    const float* __restrict__ f3, float* __restrict__ U,
    const float* __restrict__ mb, u16* __restrict__ mbb, float* __restrict__ mb2,
    u32* __restrict__ minkey) {
    int bid = blockIdx.x, tid = threadIdx.x;
    if (bid < 16384) {
        float4 v = ((const float4*)(mb + (size_t)bid * 1024))[tid];
        ushort4 o;
        o.x = f2bf(v.x); o.y = f2bf(v.y); o.z = f2bf(v.z); o.w = f2bf(v.w);
        ((ushort4*)(mbb + (size_t)bid * 1024))[tid] = o;
        float ssq = v.x * v.x + v.y * v.y + v.z * v.z + v.w * v.w;
        for (int s = 32; s; s >>= 1) ssq += __shfl_down(ssq, s);
        __shared__ float sm[4];
        if ((tid & 63) == 0) sm[tid >> 6] = ssq;
        __syncthreads();
        if (tid == 0) mb2[bid] = sm[0] + sm[1] + sm[2] + sm[3];
        if (bid < 25) {
            int i = bid * 256 + tid;
            if (i < 6400) minkey[i] = 0xFFFFFFFFu;
        }
    } else {
        int idx = (bid - 16384) * 256 + tid;
        if (idx >= 8 * 512 * 196) return;
        int b = idx / (512 * 196);
        int rem = idx % (512 * 196);
        int t = rem / 196;
        int yx = rem % 196;
        int y = yx / 14, x = yx % 14;
        const float* p0 = f3 + ((size_t)(b * 1024 + 2 * t)) * 196;
        const float* p1 = p0 + 196;
        float s = 0.f;
        #pragma unroll
        for (int dy = -1; dy <= 1; ++dy) {
            int yy = y + dy; if ((unsigned)yy >= 14u) continue;
            #pragma unroll
            for (int dx = -1; dx <= 1; ++dx) {
                int xx = x + dx; if ((unsigned)xx >= 14u) continue;
                s += p0[yy * 14 + xx] + p1[yy * 14 + xx];
            }
        }
        U[idx] = s;
    }
}

// q[n, 0:512] = weighted 3x3 mean of feat2; q[n, 512+t] = bilinear(U)[h,w]/18
__global__ __launch_bounds__(256) void q_kernel(const float* __restrict__ feat2, const float* __restrict__ U,
                                                u16* __restrict__ qb, float* __restrict__ qn2) {
    int n = blockIdx.x;
    int b = n / 784;
    int hw = n % 784;
    int h = hw / 28, w = hw % 28;
    int tid = threadIdx.x;
    int y0, y1, x0, x1; float wy0, wy1, wx0, wx1;
    taps(h, y0, y1, wy0, wy1);
    taps(w, x0, x1, wx0, wx1);
    float ssq = 0.f;
    #pragma unroll
    for (int k = 0; k < 4; ++k) {
        int d = tid + k * 256;
        float val;
        if (d < 512) {
            const float* p = feat2 + ((size_t)(b * 512 + d)) * 784;
            float s = 0.f;
            #pragma unroll
            for (int di = -1; di <= 1; ++di) {
                int y = h + di; if ((unsigned)y >= 28u) continue;
                #pragma unroll
                for (int dj = -1; dj <= 1; ++dj) {
                    int x = w + dj; if ((unsigned)x >= 28u) continue;
                    float v = p[y * 28 + x];
                    s += (di == 0 && dj == 0) ? 2.f * v : v;
                }
            }
            val = s * 0.1f;
        } else {
            const float* up = U + ((size_t)(b * 512 + (d - 512))) * 196;
            float v00 = up[y0 * 14 + x0], v01 = up[y0 * 14 + x1];
            float v10 = up[y1 * 14 + x0], v11 = up[y1 * 14 + x1];
            val = (wy0 * (wx0 * v00 + wx1 * v01) + wy1 * (wx0 * v10 + wx1 * v11)) * (1.f / 18.f);
        }
        ssq += val * val;
        qb[(size_t)n * 1024 + d] = f2bf(val);
    }
    for (int s = 32; s; s >>= 1) ssq += __shfl_down(ssq, s);
    __shared__ float sm[4];
    if ((tid & 63) == 0) sm[tid >> 6] = ssq;
    __syncthreads();
    if (tid == 0) qn2[n] = sm[0] + sm[1] + sm[2] + sm[3];
}

// 256x256-tile BK=64 bf16 MFMA GEMM, BURST schedule: per K-tile, issue ALL
// 24 frag ds_reads + ALL 8 next-tile global_load_lds up front, then 4 MFMA
// quadrants gated by counted lgkmcnt(12)/(4)/(0). 1 barrier + 1 vmcnt(0)
// per tile. Plain double-buffer (66KB LDS). Fused min epilogue.
// M=6400 (q rows, 6272 real), N=16384, K=1024 -> 16 K-tiles.
__global__ __launch_bounds__(512, 1) void gemm_min_kernel(
    const u16* __restrict__ qb, const u16* __restrict__ mbb,
    const float* __restrict__ qn2, const float* __restrict__ mb2,
    u32* __restrict__ minkeys) {
    __shared__ __align__(16) u16 As[2][16384];   // [buf][256 rows x 64 cols]
    __shared__ __align__(16) u16 Bs[2][16384];
    __shared__ u32 rowmin[256];

    const int tid = threadIdx.x;
    const int wid = tid >> 6;
    const int lane = tid & 63;
    const int wm = wid >> 2;   // 2 M-waves
    const int wn = wid & 3;    // 4 N-waves

    // XCD-aware bijective swizzle: 1600 blocks, 8 XCDs, 200/XCD.
    const int flat = blockIdx.x;
    const int swz = (flat & 7) * 200 + (flat >> 3);
    const int q0 = (swz % 25) * 256;   // q-row (M) panel
    const int m0 = (swz / 25) * 256;   // memory-bank (N) panel

    // staging: half-tile = 128 rows x 64 cols = 16 KB; 2 gload_lds/thread.
    // LDS dest linear; global source slot XOR-swizzled with row&7 (= lane>>3).
    const int rA = wid * 16 + (lane >> 3);            // + j*8
    const int srcslot = (lane & 7) ^ (lane >> 3);
    size_t baseA[2], baseB[2];
    u32 ldst[2];
    #pragma unroll
    for (int j = 0; j < 2; ++j) {
        baseA[j] = (size_t)(q0 + rA + j * 8) * 1024 + srcslot * 8;
        baseB[j] = (size_t)(m0 + rA + j * 8) * 1024 + srcslot * 8;
        ldst[j] = (wid * 2 + j) * 512;                // u16 idx, wave-uniform
    }

    #define STAGE_A(T, H) { const int _t = (T), _h = (H); \
        GLD16(qb + baseA[0] + (size_t)_h * 131072 + _t * 64, &As[_t & 1][_h * 8192 + ldst[0]]); \
        GLD16(qb + baseA[1] + (size_t)_h * 131072 + _t * 64, &As[_t & 1][_h * 8192 + ldst[1]]); }
    #define STAGE_B(T, H) { const int _t = (T), _h = (H); \
        GLD16(mbb + baseB[0] + (size_t)_h * 131072 + _t * 64, &Bs[_t & 1][_h * 8192 + ldst[0]]); \
        GLD16(mbb + baseB[1] + (size_t)_h * 131072 + _t * 64, &Bs[_t & 1][_h * 8192 + ldst[1]]); }

    // fragment read addressing (row&7 == lane&7 for all frags)
    const u32 arow = (u32)(wm * 128 + (lane & 15)) * 64;   // + m*1024
    const u32 brow = (u32)(wn * 64 + (lane & 15)) * 64;    // + n*1024
    const u32 sl0 = (u32)(((lane >> 4)) ^ (lane & 7)) * 8;       // kk=0
    const u32 sl1 = (u32)((4 + (lane >> 4)) ^ (lane & 7)) * 8;   // kk=1

    f32x4 acc[8][4] = {};
    bf16x8 alo[4][2], ahi[4][2], b01[2][2], b23[2][2];

    #define MFMA8(M0, AARR, BARR, N0) \
        _Pragma("unroll") for (int m = 0; m < 4; ++m) \
            _Pragma("unroll") for (int n = 0; n < 2; ++n) { \
                acc[(M0) + m][(N0) + n] = __builtin_amdgcn_mfma_f32_16x16x32_bf16(AARR[m][0], BARR[n][0], acc[(M0) + m][(N0) + n], 0, 0, 0); \
                acc[(M0) + m][(N0) + n] = __builtin_amdgcn_mfma_f32_16x16x32_bf16(AARR[m][1], BARR[n][1], acc[(M0) + m][(N0) + n], 0, 0, 0); }

    // ---- prologue: stage tile 0, wait, barrier
    STAGE_A(0, 0); STAGE_A(0, 1);
    STAGE_B(0, 0); STAGE_B(0, 1);
    asm volatile("s_waitcnt vmcnt(0)" ::: "memory");
    __builtin_amdgcn_s_barrier();
    __builtin_amdgcn_sched_barrier(0);

    for (int t = 0; t < 16; ++t) {
        const u16* Ab = &As[t & 1][0];
        const u16* Bb = &Bs[t & 1][0];

        // ---- burst: all 24 frag reads, in lgkm-count order alo,b01,ahi,b23
        #pragma unroll
        for (int m = 0; m < 4; ++m) {
            alo[m][0] = *(const bf16x8*)&Ab[arow + m * 1024 + sl0];
            alo[m][1] = *(const bf16x8*)&Ab[arow + m * 1024 + sl1];
        }
        #pragma unroll
        for (int n = 0; n < 2; ++n) {
            b01[n][0] = *(const bf16x8*)&Bb[brow + n * 1024 + sl0];
            b01[n][1] = *(const bf16x8*)&Bb[brow + n * 1024 + sl1];
        }
        #pragma unroll
        for (int m = 0; m < 4; ++m) {
            ahi[m][0] = *(const bf16x8*)&Ab[arow + (4 + m) * 1024 + sl0];
            ahi[m][1] = *(const bf16x8*)&Ab[arow + (4 + m) * 1024 + sl1];
        }
        #pragma unroll
        for (int n = 0; n < 2; ++n) {
            b23[n][0] = *(const bf16x8*)&Bb[brow + (2 + n) * 1024 + sl0];
            b23[n][1] = *(const bf16x8*)&Bb[brow + (2 + n) * 1024 + sl1];
        }
        // ---- stage ALL of tile t+1 (other buffer; t-1 reads fully retired)
        if (t < 15) {
            STAGE_A(t + 1, 0); STAGE_A(t + 1, 1);
            STAGE_B(t + 1, 0); STAGE_B(t + 1, 1);
        }

        // ---- Q1: alo x b01 (needs first 12 reads)
        asm volatile("s_waitcnt lgkmcnt(12)" ::: "memory");
        __builtin_amdgcn_sched_barrier(0);
        __builtin_amdgcn_s_setprio(1);
        MFMA8(0, alo, b01, 0);
        __builtin_amdgcn_s_setprio(0);
        // ---- Q2: ahi x b01 (needs first 20)
        asm volatile("s_waitcnt lgkmcnt(4)" ::: "memory");
        __builtin_amdgcn_sched_barrier(0);
        __builtin_amdgcn_s_setprio(1);
        MFMA8(4, ahi, b01, 0);
        __builtin_amdgcn_s_setprio(0);
        // ---- Q3+Q4: all reads retired
        asm volatile("s_waitcnt lgkmcnt(0)" ::: "memory");
        __builtin_amdgcn_sched_barrier(0);
        __builtin_amdgcn_s_setprio(1);
        MFMA8(4, ahi, b23, 2);
        MFMA8(0, alo, b23, 2);
        __builtin_amdgcn_s_setprio(0);

        // ---- tile end: next tile landed, publish buffers
        if (t < 15) { asm volatile("s_waitcnt vmcnt(0)" ::: "memory"); }
        __builtin_amdgcn_s_barrier();
        __builtin_amdgcn_sched_barrier(0);
    }

    // ---- epilogue: fused min over memory dim
    if (tid < 256) rowmin[tid] = 0xFFFFFFFFu;
    __syncthreads();

    float mb2v[4];
    #pragma unroll
    for (int n = 0; n < 4; ++n) mb2v[n] = mb2[m0 + wn * 64 + n * 16 + (lane & 15)];

    #pragma unroll
    for (int m = 0; m < 8; ++m) {
        #pragma unroll
        for (int r = 0; r < 4; ++r) {
            const int qrow = wm * 128 + m * 16 + (lane >> 4) * 4 + r;
            const float qq = qn2[q0 + qrow];
            float v = 3.4e38f;
            #pragma unroll
            for (int n = 0; n < 4; ++n) {
                float d2 = qq + mb2v[n] - 2.0f * acc[m][n][r];
                v = fminf(v, d2);
            }
            #pragma unroll
            for (int s = 1; s < 16; s <<= 1) v = fminf(v, __shfl_xor(v, s));
            if ((lane & 15) == 0) atomicMin(&rowmin[qrow], flipf(v));
        }
    }
    __syncthreads();
    if (tid < 256) atomicMin(minkeys + q0 + tid, rowmin[tid]);
}

// per-image max + write patch scores
__global__ __launch_bounds__(256) void final_kernel(const u32* __restrict__ keys, float* __restrict__ out) {
    int b = blockIdx.x, tid = threadIdx.x;
    float mx = -3.4e38f;
    for (int i = tid; i < 784; i += 256) {
        float f = unflipf(keys[b * 784 + i]);
        out[8 + b * 784 + i] = f;
        mx = fmaxf(mx, f);
    }
    for (int s = 32; s; s >>= 1) mx = fmaxf(mx, __shfl_down(mx, s));
    __shared__ float sm[4];
    if ((tid & 63) == 0) sm[tid >> 6] = mx;
    __syncthreads();
    if (tid == 0) out[b] = fmaxf(fmaxf(sm[0], sm[1]), fmaxf(sm[2], sm[3]));
}

extern "C" void kernel_launch(void* const* d_in, const int* in_sizes, int n_in,
                              void* d_out, int out_size, void* d_ws, size_t ws_size,
                              hipStream_t stream) {
    const float* feat2 = (const float*)d_in[0];   // [8,512,28,28]
    const float* feat3 = (const float*)d_in[1];   // [8,1024,14,14]
    const float* mb    = (const float*)d_in[2];   // [16384,1024]
    float* out = (float*)d_out;                   // [8] image + [8,28,28] patch

    char* ws = (char*)d_ws;
    float* U      = (float*)(ws);                  // 3,211,264 B
    u16*   qb     = (u16*)  (ws + 3211264);        // 6400*1024*2 = 13,107,200 B (pad rows unused)
    u16*   mbb    = (u16*)  (ws + 16318464);       // 33,554,432 B
    float* qn2    = (float*)(ws + 49872896);       // 25,088 B
    float* mb2    = (float*)(ws + 49897984);       // 65,536 B
    u32*   minkey = (u32*)  (ws + 49963520);       // 25,600 B

    prep_kernel<<<19520, 256, 0, stream>>>(feat3, U, mb, mbb, mb2, minkey);
    q_kernel<<<6272, 256, 0, stream>>>(feat2, U, qb, qn2);
    gemm_min_kernel<<<1600, 512, 0, stream>>>(qb, mbb, qn2, mb2, minkey);
    final_kernel<<<8, 256, 0, stream>>>(minkey, out);
}